// Round 6
// baseline (56696.979 us; speedup 1.0000x reference)
//
#include <hip/hip_runtime.h>
#include <math.h>

#define TT 8192
#define DD 128
#define HH 1024
#define RINGN 64           // ring slots (power of 2); lag bound 48 via amortized checks
#define NA 64              // layer-0 workgroups
#define NB 128             // layer-1 workgroups
#define NC 16              // decoder workgroups
#define NWG (NA + NB + NC)

// d_ws layout (bytes):
//   [0)      b_cons u32[128]   B's consumption epoch of h0 (ring reuse)
//   [512)    c_cons u32[16]    C's consumption epoch of h1
//   [4096)               h0A ull[RINGN][HH]  replica swept by A (cycle edge)
//   [4096+0.5MB)         h0B ull[RINGN][HH]  replica swept by B (feed-fwd)
//   [4096+1.0MB)         h1B ull[RINGN][HH]  replica swept by B (cycle edge)
//   [4096+1.5MB)         h1C ull[RINGN][HH]  replica swept by C (feed-fwd)
// Protocol: producers fire-and-forget (value f32 | epoch u32) 8B relaxed
// agent-scope atomic pairs into each replica. One dedicated wave per consumer
// WG sweeps its replica (lane l owns pairs [16l,16l+16) -> 1:1 with producer
// WGs for h0), staging matched values into LDS. ONE barrier per step, then
// all waves compute. No fences, no flags, no relays on the critical path.

typedef unsigned long long ull;

__device__ __forceinline__ ull ldpair(const ull* p) {
  return __hip_atomic_load(p, __ATOMIC_RELAXED, __HIP_MEMORY_SCOPE_AGENT);
}
__device__ __forceinline__ void stpair(ull* p, float v, unsigned e) {
  ull u = ((ull)e << 32) | (ull)__float_as_uint(v);
  __hip_atomic_store(p, u, __ATOMIC_RELAXED, __HIP_MEMORY_SCOPE_AGENT);
}
__device__ __forceinline__ unsigned ldflag(const unsigned* p) {
  return __hip_atomic_load(p, __ATOMIC_RELAXED, __HIP_MEMORY_SCOPE_AGENT);
}
__device__ __forceinline__ void stflag(unsigned* p, unsigned v) {
  __hip_atomic_store(p, v, __ATOMIC_RELAXED, __HIP_MEMORY_SCOPE_AGENT);
}
__device__ __forceinline__ float sigm(float x) { return 1.0f / (1.0f + expf(-x)); }
__device__ __forceinline__ float softplusf(float x) {
  return x > 0.0f ? x + log1pf(expf(-x)) : log1pf(expf(x));
}

// sweep 16 pairs at lds[base..base+16) from ring slot sl, expecting epoch ee;
// deposit matched values. Loops until all 16 matched.
__device__ __forceinline__ void sweep16(const ull* sl, int base, unsigned ee,
                                        float* lds, const int* pos) {
  unsigned pend = 0xFFFFu;
  do {
    #pragma unroll
    for (int i = 0; i < 16; ++i) {
      if (pend & (1u << i)) {
        const ull u = ldpair(sl + base + i);
        if ((unsigned)(u >> 32) == ee) {
          lds[pos[i]] = __uint_as_float((unsigned)u);
          pend &= ~(1u << i);
        }
      }
    }
  } while (pend);
}

#define FMA16(W)                                                      \
  a0 = fmaf(W[0][4*i+0], h4.x, a0); a0 = fmaf(W[0][4*i+1], h4.y, a0); \
  a0 = fmaf(W[0][4*i+2], h4.z, a0); a0 = fmaf(W[0][4*i+3], h4.w, a0); \
  a1 = fmaf(W[1][4*i+0], h4.x, a1); a1 = fmaf(W[1][4*i+1], h4.y, a1); \
  a1 = fmaf(W[1][4*i+2], h4.z, a1); a1 = fmaf(W[1][4*i+3], h4.w, a1); \
  a2 = fmaf(W[2][4*i+0], h4.x, a2); a2 = fmaf(W[2][4*i+1], h4.y, a2); \
  a2 = fmaf(W[2][4*i+2], h4.z, a2); a2 = fmaf(W[2][4*i+3], h4.w, a2); \
  a3 = fmaf(W[3][4*i+0], h4.x, a3); a3 = fmaf(W[3][4*i+1], h4.y, a3); \
  a3 = fmaf(W[3][4*i+2], h4.z, a3); a3 = fmaf(W[3][4*i+3], h4.w, a3);

__global__ void __launch_bounds__(512, 1) deepar_persistent(
    const float* __restrict__ obs,
    const float* __restrict__ Wih0, const float* __restrict__ Whh0, const float* __restrict__ b0,
    const float* __restrict__ Wih1, const float* __restrict__ Whh1, const float* __restrict__ b1,
    const float* __restrict__ Wdec, const float* __restrict__ bdec,
    float* __restrict__ out,
    unsigned* b_cons, unsigned* c_cons,
    ull* h0A, ull* h0B, ull* h1B, ull* h1C)
{
  __shared__ __align__(16) float hx[2][2304];

  const int wg   = blockIdx.x;
  const int tid  = threadIdx.x;
  const int wid  = tid >> 6;
  const int lane = tid & 63;

  if (wg < NA) {
    //========== Group A: layer-0. 16 j's/WG; 32 lanes per j ==========
    const int rg = tid >> 5;          // 0..15 (j within WG)
    const int q  = tid & 31;          // 36-wide k-slice of [h0(1024); x(128)]
    const int j  = wg * 16 + rg;
    const int k0 = q * 36;
    float w[4][36];
    #pragma unroll
    for (int i = 0; i < 9; ++i) {
      const int kb = k0 + 4 * i;
      #pragma unroll
      for (int r = 0; r < 4; ++r) {
        const float* src = (kb < HH) ? (Whh0 + (size_t)(r * HH + j) * HH + kb)
                                     : (Wih0 + (size_t)(r * HH + j) * DD + (kb - HH));
        const float4 v = *(const float4*)src;
        w[r][4*i+0] = v.x; w[r][4*i+1] = v.y; w[r][4*i+2] = v.z; w[r][4*i+3] = v.w;
      }
    }
    float bs[4];
    #pragma unroll
    for (int r = 0; r < 4; ++r) bs[r] = b0[r * HH + j];
    float creg = 0.0f;
    int pos[16];                       // LDS positions for sweep lane (unpadded)
    #pragma unroll
    for (int i = 0; i < 16; ++i) pos[i] = lane * 16 + i;

    for (int t = 0; t < TT; ++t) {
      float a0 = 0.f, a1 = 0.f, a2 = 0.f, a3 = 0.f;
      if (t > 0) {                     // x-part: cached loads, overlaps the sweep
        const float* obr = obs + (size_t)(t - 1) * DD;
        #pragma unroll
        for (int i = 0; i < 9; ++i) {
          const int kb = k0 + 4 * i;
          if (kb >= HH) { const float4 h4 = *(const float4*)(obr + (kb - HH)); FMA16(w) }
        }
      }
      // wave1: amortized ring-reuse backpressure (B consumed h0(t-32))
      if (wid == 1 && ((t & 15) == 0) && t >= 48) {
        const unsigned need = (unsigned)(t - 32);
        while (!__all((ldflag(&b_cons[lane]) >= need) &
                      (ldflag(&b_cons[lane + 64]) >= need))) {}
      }
      float* Lb = hx[t & 1];
      // wave0: sweep own replica of h0(t-1) -> LDS (1-hop cycle edge)
      if (wid == 0 && t > 0)
        sweep16(h0A + (size_t)((t - 1) & (RINGN - 1)) * HH, lane * 16,
                (unsigned)t, Lb, pos);
      __syncthreads();                 // the only barrier per step
      if (t > 0) {
        #pragma unroll
        for (int i = 0; i < 9; ++i) {
          const int kb = k0 + 4 * i;
          if (kb < HH) { const float4 h4 = *(const float4*)&Lb[kb]; FMA16(w) }
        }
      }
      #pragma unroll
      for (int s = 1; s < 32; s <<= 1) {
        a0 += __shfl_xor(a0, s); a1 += __shfl_xor(a1, s);
        a2 += __shfl_xor(a2, s); a3 += __shfl_xor(a3, s);
      }
      if (q == 0) {
        const float ig = sigm(a0 + bs[0]);
        const float fg = sigm(a1 + bs[1]);
        const float gg = tanhf(a2 + bs[2]);
        const float og = sigm(a3 + bs[3]);
        creg = fg * creg + ig * gg;
        const float hv = og * tanhf(creg);
        const size_t off = (size_t)(t & (RINGN - 1)) * HH + j;
        const unsigned ep = (unsigned)(t + 1);
        stpair(&h0A[off], hv, ep);     // replica for A's own sweep
        stpair(&h0B[off], hv, ep);     // replica for B
      }
    }

  } else if (wg < NA + NB) {
    //========== Group B: layer-1. 8 j's/WG; 64 lanes per j ==========
    const int rg = tid >> 6;          // 0..7
    const int q  = tid & 63;          // 32-wide k-slice of [h0(t); h1(t-1)]
    const int s_ = wg - NA;
    const int j  = s_ * 8 + rg;
    const int k0 = q * 32;
    float w[4][32];
    #pragma unroll
    for (int i = 0; i < 8; ++i) {
      const int kb = k0 + 4 * i;
      #pragma unroll
      for (int r = 0; r < 4; ++r) {
        const float* src = (kb < HH) ? (Wih1 + (size_t)(r * HH + j) * HH + kb)
                                     : (Whh1 + (size_t)(r * HH + j) * HH + (kb - HH));
        const float4 v = *(const float4*)src;
        w[r][4*i+0] = v.x; w[r][4*i+1] = v.y; w[r][4*i+2] = v.z; w[r][4*i+3] = v.w;
      }
    }
    float bs[4];
    #pragma unroll
    for (int r = 0; r < 4; ++r) bs[r] = b1[r * HH + j];
    float creg = 0.0f;
    // LDS: h0 element m at m+4*(m>>5); h1 element m at 1152+m+4*(m>>5)
    int posH0[16], posH1[16];
    #pragma unroll
    for (int i = 0; i < 16; ++i) {
      const int m = lane * 16 + i;
      posH0[i] = m + 4 * (m >> 5);
      posH1[i] = 1152 + m + 4 * (m >> 5);
    }
    const int baseB = (q < 32) ? q * 36 : 1152 + (q - 32) * 36;

    for (int t = 0; t < TT; ++t) {
      // wave2: amortized backpressure (C consumed h1(t-32))
      if (wid == 2 && ((t & 15) == 0) && t >= 48) {
        const unsigned need = (unsigned)(t - 32);
        while (!__all((lane >= NC) | (ldflag(&c_cons[lane]) >= need))) {}
      }
      float* Lb = hx[t & 1];
      if (wid == 0) {                  // cycle edge: h1(t-1)
        if (t > 0)
          sweep16(h1B + (size_t)((t - 1) & (RINGN - 1)) * HH, lane * 16,
                  (unsigned)t, Lb, posH1);
        else {
          #pragma unroll
          for (int i = 0; i < 16; ++i) Lb[posH1[i]] = 0.0f;
        }
      } else if (wid == 1) {           // feed-forward: h0(t)
        sweep16(h0B + (size_t)(t & (RINGN - 1)) * HH, lane * 16,
                (unsigned)(t + 1), Lb, posH0);
      }
      __syncthreads();
      if (tid == 0) stflag(&b_cons[s_], (unsigned)(t + 1));   // h0(t) consumed
      float a0 = 0.f, a1 = 0.f, a2 = 0.f, a3 = 0.f;
      #pragma unroll
      for (int i = 0; i < 8; ++i) {
        const float4 h4 = *(const float4*)&Lb[baseB + 4 * i];
        FMA16(w)
      }
      #pragma unroll
      for (int s = 1; s < 64; s <<= 1) {
        a0 += __shfl_xor(a0, s); a1 += __shfl_xor(a1, s);
        a2 += __shfl_xor(a2, s); a3 += __shfl_xor(a3, s);
      }
      if (q == 0) {
        const float ig = sigm(a0 + bs[0]);
        const float fg = sigm(a1 + bs[1]);
        const float gg = tanhf(a2 + bs[2]);
        const float og = sigm(a3 + bs[3]);
        creg = fg * creg + ig * gg;
        const float hv = og * tanhf(creg);
        const size_t off = (size_t)(t & (RINGN - 1)) * HH + j;
        const unsigned ep = (unsigned)(t + 1);
        stpair(&h1B[off], hv, ep);     // replica for B's own sweep
        stpair(&h1C[off], hv, ep);     // replica for C
      }
    }

  } else {
    //========== Group C: decoder. 16 rows/WG; 2 rows per 64-lane group ==========
    const int rg = tid >> 6;          // 0..7
    const int q  = tid & 63;          // 16-wide k-slice of h1
    const int cg = wg - NA - NB;
    const int row0 = cg * 16 + 2 * rg;
    const int k0 = q * 16;
    float w[2][16];
    #pragma unroll
    for (int i = 0; i < 4; ++i) {
      const int kb = k0 + 4 * i;
      #pragma unroll
      for (int r = 0; r < 2; ++r) {
        const float4 v = *(const float4*)(Wdec + (size_t)(row0 + r) * HH + kb);
        w[r][4*i+0] = v.x; w[r][4*i+1] = v.y; w[r][4*i+2] = v.z; w[r][4*i+3] = v.w;
      }
    }
    const float bs0 = bdec[row0], bs1 = bdec[row0 + 1];
    int pos[16];                       // padded: m + 4*(m>>4) = lane*20+i
    #pragma unroll
    for (int i = 0; i < 16; ++i) pos[i] = lane * 20 + i;

    for (int t = 0; t < TT; ++t) {
      float* Lb = hx[t & 1];
      if (wid == 0)                    // feed-forward: h1(t)
        sweep16(h1C + (size_t)(t & (RINGN - 1)) * HH, lane * 16,
                (unsigned)(t + 1), Lb, pos);
      __syncthreads();
      if (tid == 0) stflag(&c_cons[cg], (unsigned)(t + 1));   // h1(t) consumed
      float a0 = 0.f, a1 = 0.f;
      {
        const int base = q * 20;
        #pragma unroll
        for (int i = 0; i < 4; ++i) {
          const float4 h4 = *(const float4*)&Lb[base + 4 * i];
          a0 = fmaf(w[0][4*i+0], h4.x, a0); a0 = fmaf(w[0][4*i+1], h4.y, a0);
          a0 = fmaf(w[0][4*i+2], h4.z, a0); a0 = fmaf(w[0][4*i+3], h4.w, a0);
          a1 = fmaf(w[1][4*i+0], h4.x, a1); a1 = fmaf(w[1][4*i+1], h4.y, a1);
          a1 = fmaf(w[1][4*i+2], h4.z, a1); a1 = fmaf(w[1][4*i+3], h4.w, a1);
        }
      }
      #pragma unroll
      for (int s = 1; s < 64; s <<= 1) { a0 += __shfl_xor(a0, s); a1 += __shfl_xor(a1, s); }
      if (q == 0) {
        const float z0 = a0 + bs0;
        const float z1 = a1 + bs1;
        if (row0 < DD) {
          out[(size_t)t * DD + row0]     = z0;
          out[(size_t)t * DD + row0 + 1] = z1;
        } else {
          out[(size_t)TT * DD + (size_t)t * DD + (row0 - DD)]     = softplusf(z0) + 1e-4f;
          out[(size_t)TT * DD + (size_t)t * DD + (row0 - DD) + 1] = softplusf(z1) + 1e-4f;
        }
      }
    }
  }
}

extern "C" void kernel_launch(void* const* d_in, const int* in_sizes, int n_in,
                              void* d_out, int out_size, void* d_ws, size_t ws_size,
                              hipStream_t stream) {
  const float* obs  = (const float*)d_in[0];
  const float* Wih0 = (const float*)d_in[1];
  const float* Whh0 = (const float*)d_in[2];
  const float* b0   = (const float*)d_in[3];
  const float* Wih1 = (const float*)d_in[4];
  const float* Whh1 = (const float*)d_in[5];
  const float* b1   = (const float*)d_in[6];
  const float* Wdec = (const float*)d_in[7];
  const float* bdec = (const float*)d_in[8];
  float* out = (float*)d_out;

  const size_t RB = (size_t)RINGN * HH * 8;   // bytes per ring replica (512 KB)
  unsigned char* ws = (unsigned char*)d_ws;
  unsigned* b_cons = (unsigned*)(ws);
  unsigned* c_cons = (unsigned*)(ws + 512);
  ull* h0A = (ull*)(ws + 4096);
  ull* h0B = (ull*)(ws + 4096 + RB);
  ull* h1B = (ull*)(ws + 4096 + 2 * RB);
  ull* h1C = (ull*)(ws + 4096 + 3 * RB);

  // zero flags + all ring replicas every call (epochs restart; replay-safe)
  hipMemsetAsync(ws, 0, 4096 + 4 * RB, stream);

  hipLaunchKernelGGL(deepar_persistent, dim3(NWG), dim3(512), 0, stream,
                     obs, Wih0, Whh0, b0, Wih1, Whh1, b1, Wdec, bdec, out,
                     b_cons, c_cons, h0A, h0B, h1B, h1C);
}

// Round 7
// 31525.604 us; speedup vs baseline: 1.7984x; 1.7984x over previous
//
#include <hip/hip_runtime.h>
#include <math.h>

#define TT 8192
#define DD 128
#define HH 1024
#define RINGN 64           // ring slots; reuse window 48 enforced via amortized checks
#define NA 64              // layer-0 workgroups
#define NB 128             // layer-1 workgroups
#define NC 16              // decoder workgroups
#define NWG (NA + NB + NC)

// d_ws layout (bytes):
//   [0)     b_cons u32[128]  B's consumption epoch of h0 (ring reuse)
//   [512)   c_cons u32[16]   C's consumption epoch of h1
//   [1024)  a_fA u32[64]     A-step flags, replica polled by A-group
//   [1536)  a_fB u32[64]     replica polled by B-group
//   [2048)  b_fB u32[128]    B-step flags, replica polled by B-group
//   [2560)  b_fC u32[128]    replica polled by C-group
//   [4096)            h0A ull[RINGN][HH]   (value f32 | epoch u32) pairs
//   [4096+0.5MB)      h0B
//   [4096+1.0MB)      h1B
//   [4096+1.5MB)      h1C
// Protocol: producers store pairs (relaxed 8B agent atomics), raw s_barrier
// (execution-only, NO vmcnt drain), then per-WG flag stores. Flag ordering vs
// pairs is NOT guaranteed -- consumers epoch-validate every pair after the
// flag gate and retry narrowly. Detect = one wave polling 64/128 flags
// (few hot lines per WG). Staging is stride-1 into LDS (no bank conflicts).

typedef unsigned long long ull;

__device__ __forceinline__ ull ldpair(const ull* p) {
  return __hip_atomic_load(p, __ATOMIC_RELAXED, __HIP_MEMORY_SCOPE_AGENT);
}
__device__ __forceinline__ void stpair(ull* p, float v, unsigned e) {
  ull u = ((ull)e << 32) | (ull)__float_as_uint(v);
  __hip_atomic_store(p, u, __ATOMIC_RELAXED, __HIP_MEMORY_SCOPE_AGENT);
}
__device__ __forceinline__ unsigned ldflag(const unsigned* p) {
  return __hip_atomic_load(p, __ATOMIC_RELAXED, __HIP_MEMORY_SCOPE_AGENT);
}
__device__ __forceinline__ void stflag(unsigned* p, unsigned v) {
  __hip_atomic_store(p, v, __ATOMIC_RELAXED, __HIP_MEMORY_SCOPE_AGENT);
}
__device__ __forceinline__ float sigm(float x) { return 1.0f / (1.0f + expf(-x)); }
__device__ __forceinline__ float softplusf(float x) {
  return x > 0.0f ? x + log1pf(expf(-x)) : log1pf(expf(x));
}

#define FMA16(W)                                                      \
  a0 = fmaf(W[0][4*i+0], h4.x, a0); a0 = fmaf(W[0][4*i+1], h4.y, a0); \
  a0 = fmaf(W[0][4*i+2], h4.z, a0); a0 = fmaf(W[0][4*i+3], h4.w, a0); \
  a1 = fmaf(W[1][4*i+0], h4.x, a1); a1 = fmaf(W[1][4*i+1], h4.y, a1); \
  a1 = fmaf(W[1][4*i+2], h4.z, a1); a1 = fmaf(W[1][4*i+3], h4.w, a1); \
  a2 = fmaf(W[2][4*i+0], h4.x, a2); a2 = fmaf(W[2][4*i+1], h4.y, a2); \
  a2 = fmaf(W[2][4*i+2], h4.z, a2); a2 = fmaf(W[2][4*i+3], h4.w, a2); \
  a3 = fmaf(W[3][4*i+0], h4.x, a3); a3 = fmaf(W[3][4*i+1], h4.y, a3); \
  a3 = fmaf(W[3][4*i+2], h4.z, a3); a3 = fmaf(W[3][4*i+3], h4.w, a3);

__global__ void __launch_bounds__(512, 1) deepar_persistent(
    const float* __restrict__ obs,
    const float* __restrict__ Wih0, const float* __restrict__ Whh0, const float* __restrict__ b0,
    const float* __restrict__ Wih1, const float* __restrict__ Whh1, const float* __restrict__ b1,
    const float* __restrict__ Wdec, const float* __restrict__ bdec,
    float* __restrict__ out,
    unsigned* b_cons, unsigned* c_cons,
    unsigned* a_fA, unsigned* a_fB, unsigned* b_fB, unsigned* b_fC,
    ull* h0A, ull* h0B, ull* h1B, ull* h1C)
{
  __shared__ __align__(16) float hx[2][2304];

  const int wg   = blockIdx.x;
  const int tid  = threadIdx.x;
  const int wid  = tid >> 6;
  const int lane = tid & 63;

  if (wg < NA) {
    //========== Group A: layer-0. 16 j's/WG; 32 lanes per j ==========
    const int rg = tid >> 5;          // 0..15 (j within WG)
    const int q  = tid & 31;          // 36-wide k-slice of [h0(1024); x(128)]
    const int j  = wg * 16 + rg;
    const int k0 = q * 36;
    float w[4][36];
    #pragma unroll
    for (int i = 0; i < 9; ++i) {
      const int kb = k0 + 4 * i;
      #pragma unroll
      for (int r = 0; r < 4; ++r) {
        const float* src = (kb < HH) ? (Whh0 + (size_t)(r * HH + j) * HH + kb)
                                     : (Wih0 + (size_t)(r * HH + j) * DD + (kb - HH));
        const float4 v = *(const float4*)src;
        w[r][4*i+0] = v.x; w[r][4*i+1] = v.y; w[r][4*i+2] = v.z; w[r][4*i+3] = v.w;
      }
    }
    float bs[4];
    #pragma unroll
    for (int r = 0; r < 4; ++r) bs[r] = b0[r * HH + j];
    float creg = 0.0f;

    for (int t = 0; t < TT; ++t) {
      float a0 = 0.f, a1 = 0.f, a2 = 0.f, a3 = 0.f;
      if (t > 0) {                     // x-part: cached loads, overlaps detect
        const float* obr = obs + (size_t)(t - 1) * DD;
        #pragma unroll
        for (int i = 0; i < 9; ++i) {
          const int kb = k0 + 4 * i;
          if (kb >= HH) { const float4 h4 = *(const float4*)(obr + (kb - HH)); FMA16(w) }
        }
      }
      // wave1: amortized ring-reuse backpressure (B consumed h0(t-32))
      if (wid == 1 && ((t & 15) == 0) && t >= 48) {
        const unsigned need = (unsigned)(t - 32);
        while (!__all((ldflag(&b_cons[lane]) >= need) &
                      (ldflag(&b_cons[lane + 64]) >= need))) {}
      }
      // wave0: narrow detect -- poll sibling flags (64 x 4B = 4 lines)
      if (wid == 0 && t > 0) {
        const unsigned tg = (unsigned)t;
        while (!__all((lane == wg) | (ldflag(&a_fA[lane]) >= tg))) {}
      }
      __builtin_amdgcn_s_barrier();    // execution-only release (no drain)
      float* Lb = hx[t & 1];
      if (t > 0) {                     // bulk read + validate (stride-1 LDS)
        const ull* sl = h0A + (size_t)((t - 1) & (RINGN - 1)) * HH;
        const unsigned ee = (unsigned)t;
        ull u0 = ldpair(sl + tid);
        ull u1 = ldpair(sl + tid + 512);
        while ((unsigned)(u0 >> 32) != ee) u0 = ldpair(sl + tid);
        Lb[tid] = __uint_as_float((unsigned)u0);
        while ((unsigned)(u1 >> 32) != ee) u1 = ldpair(sl + tid + 512);
        Lb[tid + 512] = __uint_as_float((unsigned)u1);
      }
      __syncthreads();
      if (t > 0) {
        #pragma unroll
        for (int i = 0; i < 9; ++i) {
          const int kb = k0 + 4 * i;
          if (kb < HH) { const float4 h4 = *(const float4*)&Lb[kb]; FMA16(w) }
        }
      }
      #pragma unroll
      for (int s = 1; s < 32; s <<= 1) {
        a0 += __shfl_xor(a0, s); a1 += __shfl_xor(a1, s);
        a2 += __shfl_xor(a2, s); a3 += __shfl_xor(a3, s);
      }
      if (q == 0) {
        const float ig = sigm(a0 + bs[0]);
        const float fg = sigm(a1 + bs[1]);
        const float gg = tanhf(a2 + bs[2]);
        const float og = sigm(a3 + bs[3]);
        creg = fg * creg + ig * gg;
        const float hv = og * tanhf(creg);
        const size_t off = (size_t)(t & (RINGN - 1)) * HH + j;
        const unsigned ep = (unsigned)(t + 1);
        stpair(&h0A[off], hv, ep);
        stpair(&h0B[off], hv, ep);
      }
      asm volatile("" ::: "memory");
      __builtin_amdgcn_s_barrier();    // all pair stores ISSUED (not drained)
      if (tid == 0) { stflag(&a_fA[wg], (unsigned)(t + 1));
                      stflag(&a_fB[wg], (unsigned)(t + 1)); }
    }

  } else if (wg < NA + NB) {
    //========== Group B: layer-1. 8 j's/WG; 64 lanes per j ==========
    const int rg = tid >> 6;          // 0..7
    const int q  = tid & 63;          // 32-wide k-slice of [h0(t); h1(t-1)]
    const int s_ = wg - NA;
    const int j  = s_ * 8 + rg;
    const int k0 = q * 32;
    float w[4][32];
    #pragma unroll
    for (int i = 0; i < 8; ++i) {
      const int kb = k0 + 4 * i;
      #pragma unroll
      for (int r = 0; r < 4; ++r) {
        const float* src = (kb < HH) ? (Wih1 + (size_t)(r * HH + j) * HH + kb)
                                     : (Whh1 + (size_t)(r * HH + j) * HH + (kb - HH));
        const float4 v = *(const float4*)src;
        w[r][4*i+0] = v.x; w[r][4*i+1] = v.y; w[r][4*i+2] = v.z; w[r][4*i+3] = v.w;
      }
    }
    float bs[4];
    #pragma unroll
    for (int r = 0; r < 4; ++r) bs[r] = b1[r * HH + j];
    float creg = 0.0f;
    const int p0 = tid + 4 * (tid >> 5);     // h0 elem tid (padded)
    const int p1 = p0 + 576;                 // h0 elem tid+512
    const int p2 = p0 + 1152;                // h1 elem tid
    const int p3 = p2 + 576;                 // h1 elem tid+512
    const int baseB = (q < 32) ? q * 36 : 1152 + (q - 32) * 36;

    for (int t = 0; t < TT; ++t) {
      // wave2: amortized backpressure (C consumed h1(t-32))
      if (wid == 2 && ((t & 15) == 0) && t >= 48) {
        const unsigned need = (unsigned)(t - 32);
        while (!__all((lane >= NC) | (ldflag(&c_cons[lane]) >= need))) {}
      }
      // wave0: narrow detect on a_fB (h0(t)) + b_fB (h1(t-1))
      if (wid == 0) {
        const unsigned eA = (unsigned)(t + 1);
        const unsigned eB = (unsigned)t;
        for (;;) {
          int ok = (ldflag(&a_fB[lane]) >= eA);
          if (t > 0) {
            ok &= (lane == s_)        | (ldflag(&b_fB[lane])      >= eB);
            ok &= ((lane + 64) == s_) | (ldflag(&b_fB[lane + 64]) >= eB);
          }
          if (__all(ok)) break;
        }
      }
      __builtin_amdgcn_s_barrier();
      float* Lb = hx[t & 1];
      {
        const ull* s0 = h0B + (size_t)(t & (RINGN - 1)) * HH;
        const ull* s1 = h1B + (size_t)((t - 1) & (RINGN - 1)) * HH;
        const unsigned e0 = (unsigned)(t + 1);
        const unsigned e1 = (unsigned)t;   // t==0: memset pairs are (0,0) -> match
        ull u0 = ldpair(s0 + tid);
        ull u1 = ldpair(s0 + tid + 512);
        ull u2 = ldpair(s1 + tid);
        ull u3 = ldpair(s1 + tid + 512);
        while ((unsigned)(u0 >> 32) != e0) u0 = ldpair(s0 + tid);
        Lb[p0] = __uint_as_float((unsigned)u0);
        while ((unsigned)(u1 >> 32) != e0) u1 = ldpair(s0 + tid + 512);
        Lb[p1] = __uint_as_float((unsigned)u1);
        while ((unsigned)(u2 >> 32) != e1) u2 = ldpair(s1 + tid);
        Lb[p2] = __uint_as_float((unsigned)u2);
        while ((unsigned)(u3 >> 32) != e1) u3 = ldpair(s1 + tid + 512);
        Lb[p3] = __uint_as_float((unsigned)u3);
      }
      __syncthreads();
      if (tid == 0) stflag(&b_cons[s_], (unsigned)(t + 1));   // h0(t) consumed
      float a0 = 0.f, a1 = 0.f, a2 = 0.f, a3 = 0.f;
      #pragma unroll
      for (int i = 0; i < 8; ++i) {
        const float4 h4 = *(const float4*)&Lb[baseB + 4 * i];
        FMA16(w)
      }
      #pragma unroll
      for (int s = 1; s < 64; s <<= 1) {
        a0 += __shfl_xor(a0, s); a1 += __shfl_xor(a1, s);
        a2 += __shfl_xor(a2, s); a3 += __shfl_xor(a3, s);
      }
      if (q == 0) {
        const float ig = sigm(a0 + bs[0]);
        const float fg = sigm(a1 + bs[1]);
        const float gg = tanhf(a2 + bs[2]);
        const float og = sigm(a3 + bs[3]);
        creg = fg * creg + ig * gg;
        const float hv = og * tanhf(creg);
        const size_t off = (size_t)(t & (RINGN - 1)) * HH + j;
        const unsigned ep = (unsigned)(t + 1);
        stpair(&h1B[off], hv, ep);
        stpair(&h1C[off], hv, ep);
      }
      asm volatile("" ::: "memory");
      __builtin_amdgcn_s_barrier();
      if (tid == 0) { stflag(&b_fB[s_], (unsigned)(t + 1));
                      stflag(&b_fC[s_], (unsigned)(t + 1)); }
    }

  } else {
    //========== Group C: decoder. 16 rows/WG; 2 rows per 64-lane group ==========
    const int rg = tid >> 6;
    const int q  = tid & 63;
    const int cg = wg - NA - NB;
    const int row0 = cg * 16 + 2 * rg;
    const int k0 = q * 16;
    float w[2][16];
    #pragma unroll
    for (int i = 0; i < 4; ++i) {
      const int kb = k0 + 4 * i;
      #pragma unroll
      for (int r = 0; r < 2; ++r) {
        const float4 v = *(const float4*)(Wdec + (size_t)(row0 + r) * HH + kb);
        w[r][4*i+0] = v.x; w[r][4*i+1] = v.y; w[r][4*i+2] = v.z; w[r][4*i+3] = v.w;
      }
    }
    const float bs0 = bdec[row0], bs1 = bdec[row0 + 1];
    const int pc0 = tid + 4 * (tid >> 4);
    const int pc1 = pc0 + 640;

    for (int t = 0; t < TT; ++t) {
      if (wid == 0) {                  // detect h1(t)
        const unsigned tg = (unsigned)(t + 1);
        while (!__all((ldflag(&b_fC[lane]) >= tg) &
                      (ldflag(&b_fC[lane + 64]) >= tg))) {}
      }
      __builtin_amdgcn_s_barrier();
      float* Lb = hx[t & 1];
      {
        const ull* sl = h1C + (size_t)(t & (RINGN - 1)) * HH;
        const unsigned ee = (unsigned)(t + 1);
        ull u0 = ldpair(sl + tid);
        ull u1 = ldpair(sl + tid + 512);
        while ((unsigned)(u0 >> 32) != ee) u0 = ldpair(sl + tid);
        Lb[pc0] = __uint_as_float((unsigned)u0);
        while ((unsigned)(u1 >> 32) != ee) u1 = ldpair(sl + tid + 512);
        Lb[pc1] = __uint_as_float((unsigned)u1);
      }
      __syncthreads();
      if (tid == 0) stflag(&c_cons[cg], (unsigned)(t + 1));   // h1(t) consumed
      float a0 = 0.f, a1 = 0.f;
      {
        const int base = q * 20;
        #pragma unroll
        for (int i = 0; i < 4; ++i) {
          const float4 h4 = *(const float4*)&Lb[base + 4 * i];
          a0 = fmaf(w[0][4*i+0], h4.x, a0); a0 = fmaf(w[0][4*i+1], h4.y, a0);
          a0 = fmaf(w[0][4*i+2], h4.z, a0); a0 = fmaf(w[0][4*i+3], h4.w, a0);
          a1 = fmaf(w[1][4*i+0], h4.x, a1); a1 = fmaf(w[1][4*i+1], h4.y, a1);
          a1 = fmaf(w[1][4*i+2], h4.z, a1); a1 = fmaf(w[1][4*i+3], h4.w, a1);
        }
      }
      #pragma unroll
      for (int s = 1; s < 64; s <<= 1) { a0 += __shfl_xor(a0, s); a1 += __shfl_xor(a1, s); }
      if (q == 0) {
        const float z0 = a0 + bs0;
        const float z1 = a1 + bs1;
        if (row0 < DD) {
          out[(size_t)t * DD + row0]     = z0;
          out[(size_t)t * DD + row0 + 1] = z1;
        } else {
          out[(size_t)TT * DD + (size_t)t * DD + (row0 - DD)]     = softplusf(z0) + 1e-4f;
          out[(size_t)TT * DD + (size_t)t * DD + (row0 - DD) + 1] = softplusf(z1) + 1e-4f;
        }
      }
    }
  }
}

extern "C" void kernel_launch(void* const* d_in, const int* in_sizes, int n_in,
                              void* d_out, int out_size, void* d_ws, size_t ws_size,
                              hipStream_t stream) {
  const float* obs  = (const float*)d_in[0];
  const float* Wih0 = (const float*)d_in[1];
  const float* Whh0 = (const float*)d_in[2];
  const float* b0   = (const float*)d_in[3];
  const float* Wih1 = (const float*)d_in[4];
  const float* Whh1 = (const float*)d_in[5];
  const float* b1   = (const float*)d_in[6];
  const float* Wdec = (const float*)d_in[7];
  const float* bdec = (const float*)d_in[8];
  float* out = (float*)d_out;

  const size_t RB = (size_t)RINGN * HH * 8;   // 512 KB per ring replica
  unsigned char* ws = (unsigned char*)d_ws;
  unsigned* b_cons = (unsigned*)(ws);
  unsigned* c_cons = (unsigned*)(ws + 512);
  unsigned* a_fA   = (unsigned*)(ws + 1024);
  unsigned* a_fB   = (unsigned*)(ws + 1536);
  unsigned* b_fB   = (unsigned*)(ws + 2048);
  unsigned* b_fC   = (unsigned*)(ws + 2560);
  ull* h0A = (ull*)(ws + 4096);
  ull* h0B = (ull*)(ws + 4096 + RB);
  ull* h1B = (ull*)(ws + 4096 + 2 * RB);
  ull* h1C = (ull*)(ws + 4096 + 3 * RB);

  // zero flags + all ring replicas every call (epochs restart; replay-safe)
  hipMemsetAsync(ws, 0, 4096 + 4 * RB, stream);

  hipLaunchKernelGGL(deepar_persistent, dim3(NWG), dim3(512), 0, stream,
                     obs, Wih0, Whh0, b0, Wih1, Whh1, b1, Wdec, bdec, out,
                     b_cons, c_cons, a_fA, a_fB, b_fB, b_fC,
                     h0A, h0B, h1B, h1C);
}